// Round 2
// baseline (383.186 us; speedup 1.0000x reference)
//
#include <hip/hip_runtime.h>
#include <hip/hip_bf16.h>
#include <cstdint>
#include <cstddef>

#define AS1 __attribute__((address_space(1)))
#define AS3 __attribute__((address_space(3)))

typedef __attribute__((ext_vector_type(8))) short short8v;
typedef __attribute__((ext_vector_type(4))) float f32x4;
typedef unsigned short u16;

constexpr int kBatch = 16384;
constexpr int kNSp   = 26;
constexpr int kVocab = 50000;
constexpr int kEmb   = 64;
constexpr int kInDim = 1677;   // 26*64 + 13
constexpr int kInPad = 1728;   // padded to x64 for MFMA K
constexpr int kDense = 13;
constexpr int kH1 = 1024, kH2 = 512, kH3 = 256;
constexpr float kEps = 1e-5f;

// ---------- bf16 helpers (bits held in u16) ----------
__device__ __forceinline__ float b2f(u16 s) {
  unsigned u = ((unsigned)s) << 16;
  union { unsigned u; float f; } c; c.u = u; return c.f;
}
__device__ __forceinline__ u16 f2b(float f) {
  __hip_bfloat16 h = __float2bfloat16(f);   // RNE
  return __builtin_bit_cast(u16, h);
}

// ---------- prep: Swpc = sum_{j<1677} Wp[j] ----------
__global__ void prep_kernel(const float* __restrict__ Wp, float* __restrict__ misc) {
  __shared__ float red[256];
  float s = 0.f;
  for (int j = threadIdx.x; j < kInDim; j += 256) s += Wp[j];
  red[threadIdx.x] = s;
  __syncthreads();
  for (int k = 128; k > 0; k >>= 1) {
    if (threadIdx.x < k) red[threadIdx.x] += red[threadIdx.x + k];
    __syncthreads();
  }
  if (threadIdx.x == 0) misc[0] = red[0];
}

// ---------- transpose+pad+bf16: W[K][N] f32 -> Wt[N][Kp] bf16 ----------
__global__ void transpose_kernel(const float* __restrict__ W, u16* __restrict__ Wt,
                                 int K, int N, int Kp) {
  __shared__ float t[64][65];
  int kb = blockIdx.x * 64;
  int nb = blockIdx.y * 64;
  int c  = threadIdx.x & 63;
  int r0 = threadIdx.x >> 6;   // 0..3
  #pragma unroll
  for (int rr = 0; rr < 64; rr += 4) {
    int k = kb + rr + r0;
    t[rr + r0][c] = (k < K) ? W[(size_t)k * N + nb + c] : 0.f;
  }
  __syncthreads();
  #pragma unroll
  for (int rr = 0; rr < 64; rr += 4) {
    int n = nb + rr + r0;
    Wt[(size_t)n * Kp + kb + c] = f2b(t[c][rr + r0]);
  }
}

// ---------- gather: build x0 (bf16, padded) + per-row cross contribution ----------
__global__ void gather_kernel(const int* __restrict__ sparse, const float* __restrict__ dense,
                              const float* __restrict__ emb, const float* __restrict__ w_cross,
                              const float* __restrict__ b_cross, const float* __restrict__ Wp,
                              const float* __restrict__ misc, u16* __restrict__ x0,
                              float* __restrict__ crossc) {
  const int b = blockIdx.x;
  const int tid = threadIdx.x;
  const int idx = sparse[b * kNSp];       // only column 0 is used by the reference
  const float* wc2 = w_cross + 2 * kInDim;
  u16* xrow = x0 + (size_t)b * kInPad;
  float u = 0.f, v = 0.f;
  for (int q = tid; q < 416; q += 256) {  // 416 = 1664/4
    int p = q * 4;
    const float* src = emb + ((size_t)(p >> 6) * kVocab + idx) * kEmb + (p & 63);
    float4 val = *(const float4*)src;
    u += val.x * wc2[p] + val.y * wc2[p + 1] + val.z * wc2[p + 2] + val.w * wc2[p + 3];
    v += val.x * Wp[p]  + val.y * Wp[p + 1]  + val.z * Wp[p + 2]  + val.w * Wp[p + 3];
    ushort4 o;
    o.x = f2b(val.x); o.y = f2b(val.y); o.z = f2b(val.z); o.w = f2b(val.w);
    *(ushort4*)(xrow + p) = o;
  }
  int p = 1664 + tid;
  if (p < kInPad) {
    float val = 0.f;
    if (p < kInDim) {
      val = dense[b * kDense + (p - 1664)];
      u += val * wc2[p];
      v += val * Wp[p];
    }
    xrow[p] = f2b(val);
  }
  #pragma unroll
  for (int off = 32; off; off >>= 1) {
    u += __shfl_down(u, off, 64);
    v += __shfl_down(v, off, 64);
  }
  __shared__ float su[4], sv[4];
  int lane = tid & 63, wv = tid >> 6;
  if (lane == 0) { su[wv] = u; sv[wv] = v; }
  __syncthreads();
  if (tid == 0) {
    float uu = su[0] + su[1] + su[2] + su[3];
    float vv = sv[0] + sv[1] + sv[2] + sv[3];
    crossc[b] = (1.f + uu) * vv + b_cross[2] * misc[0];
  }
}

// ---------- per-column sums / sumsq over batch ----------
__global__ void colstats_kernel(const u16* __restrict__ X, int ld, int rpb,
                                float* __restrict__ sum, float* __restrict__ sq) {
  int c  = threadIdx.x & 63;
  int rg = threadIdx.x >> 6;   // 0..3
  int col = blockIdx.x * 64 + c;
  int r0  = blockIdx.y * rpb;
  float s = 0.f, s2 = 0.f;
  for (int r = r0 + rg; r < r0 + rpb; r += 4) {
    float v = b2f(X[(size_t)r * ld + col]);
    s += v; s2 += v * v;
  }
  __shared__ float sh[8][64];
  sh[rg][c] = s; sh[rg + 4][c] = s2;
  __syncthreads();
  if (rg == 0) atomicAdd(&sum[col], sh[0][c] + sh[1][c] + sh[2][c] + sh[3][c]);
  else if (rg == 1) atomicAdd(&sq[col], sh[4][c] + sh[5][c] + sh[6][c] + sh[7][c]);
}

// ---------- finalize BN affine: a = g*rsqrt(var+eps), c = b - a*mu ----------
__global__ void bn_fin_kernel(const float* __restrict__ sum, const float* __restrict__ sq,
                              const float* __restrict__ g, const float* __restrict__ bb,
                              int Nreal, int Npad, float invM,
                              float* __restrict__ a, float* __restrict__ c) {
  int j = blockIdx.x * 256 + threadIdx.x;
  if (j >= Npad) return;
  if (j < Nreal) {
    float mu  = sum[j] * invM;
    float var = sq[j] * invM - mu * mu;
    float aa  = g[j] * rsqrtf(var + kEps);
    a[j] = aa; c[j] = bb[j] - aa * mu;
  } else {
    a[j] = 0.f; c[j] = 0.f;   // padded columns stay exactly 0 after normalize
  }
}

// ---------- in-place normalize: X = bf16(a[col]*X + c[col]) ----------
__global__ void norm_kernel(u16* __restrict__ X, const float* __restrict__ a,
                            const float* __restrict__ c, int ld, long n8) {
  long i = (long)blockIdx.x * 256 + threadIdx.x;
  if (i >= n8) return;
  long base = i * 8;
  int col = (int)(base % ld);
  short8v v = *(const short8v*)(X + base);
  short8v o;
  #pragma unroll
  for (int e = 0; e < 8; ++e)
    o[e] = (short)f2b(a[col + e] * b2f((u16)v[e]) + c[col + e]);
  *(short8v*)(X + base) = o;
}

// ---------- bf16 MFMA GEMM: Z[M][N] = A[M][Kp] @ Bt[N][Kp]^T + bias ----------
// 128x128 tile, BK=64, 4 waves (2x2), global_load_lds staging, XOR-swizzled LDS.
__global__ __launch_bounds__(256) void gemm_kernel(
    const u16* __restrict__ A, const u16* __restrict__ Bt,
    const float* __restrict__ bias, u16* __restrict__ Z,
    int M, int N, int Kp) {
  __shared__ char lds[32768];
  char* ldsA = lds;
  char* ldsB = lds + 16384;
  const int tid  = threadIdx.x;
  const int lane = tid & 63;
  const int wv   = tid >> 6;
  const int wr = wv >> 1, wc = wv & 1;
  const int r16 = lane & 15, kg = lane >> 4;
  const int m0 = blockIdx.y * 128;
  const int n0 = blockIdx.x * 128;
  const int ldb = Kp * 2;  // bytes per row

  const char* gA = (const char*)A + (size_t)m0 * ldb;
  const char* gB = (const char*)Bt + (size_t)n0 * ldb;

  // staging: 16KB tile = 4 rounds x 256 thr x 16B; LDS linear, global pre-swizzled
  const char* srcA[4]; const char* srcB[4]; int dst[4];
  #pragma unroll
  for (int rr = 0; rr < 4; ++rr) {
    int lb  = (rr * 256 + tid) * 16;
    int row = lb >> 7;          // /128B per row (64 bf16)
    int kb  = lb & 127;
    int kbs = kb ^ ((row & 7) << 4);
    dst[rr]  = lb;
    srcA[rr] = gA + (size_t)row * ldb + kbs;
    srcB[rr] = gB + (size_t)row * ldb + kbs;
  }

  f32x4 acc[4][4];
  #pragma unroll
  for (int m = 0; m < 4; ++m)
    #pragma unroll
    for (int n = 0; n < 4; ++n) acc[m][n] = (f32x4){0.f, 0.f, 0.f, 0.f};

  for (int k0 = 0; k0 < Kp; k0 += 64) {
    __syncthreads();
    #pragma unroll
    for (int rr = 0; rr < 4; ++rr)
      __builtin_amdgcn_global_load_lds((const AS1 unsigned*)(srcA[rr] + k0 * 2),
                                       (AS3 unsigned*)(ldsA + dst[rr]), 16, 0, 0);
    #pragma unroll
    for (int rr = 0; rr < 4; ++rr)
      __builtin_amdgcn_global_load_lds((const AS1 unsigned*)(srcB[rr] + k0 * 2),
                                       (AS3 unsigned*)(ldsB + dst[rr]), 16, 0, 0);
    asm volatile("s_waitcnt vmcnt(0)" ::: "memory");
    __syncthreads();
    #pragma unroll
    for (int kk = 0; kk < 2; ++kk) {
      short8v av[4], bv[4];
      #pragma unroll
      for (int m = 0; m < 4; ++m) {
        int row = wr * 64 + m * 16 + r16;
        int kb  = (kk * 64 + kg * 16) ^ ((row & 7) << 4);
        av[m] = *(const short8v*)(ldsA + row * 128 + kb);
      }
      #pragma unroll
      for (int n = 0; n < 4; ++n) {
        int row = wc * 64 + n * 16 + r16;
        int kb  = (kk * 64 + kg * 16) ^ ((row & 7) << 4);
        bv[n] = *(const short8v*)(ldsB + row * 128 + kb);
      }
      #pragma unroll
      for (int m = 0; m < 4; ++m)
        #pragma unroll
        for (int n = 0; n < 4; ++n)
          acc[m][n] = __builtin_amdgcn_mfma_f32_16x16x32_bf16(av[m], bv[n], acc[m][n], 0, 0, 0);
    }
  }
  // epilogue: C/D layout col=lane&15, row=(lane>>4)*4+j (verified m89/m91)
  #pragma unroll
  for (int n = 0; n < 4; ++n) {
    int col = n0 + wc * 64 + n * 16 + r16;
    float bs = bias[col];
    #pragma unroll
    for (int m = 0; m < 4; ++m) {
      int rbase = m0 + wr * 64 + m * 16 + kg * 4;
      #pragma unroll
      for (int j = 0; j < 4; ++j)
        Z[(size_t)(rbase + j) * N + col] = f2b(acc[m][n][j] + bs);
    }
  }
}

// ---------- final: fold BN3 + concat-dot + sigmoid (OUTPUT IS FLOAT32) ----------
__global__ void final_kernel(const u16* __restrict__ z3, const float* __restrict__ a3,
                             const float* __restrict__ c3, const float* __restrict__ Wp,
                             const float* __restrict__ bp, const float* __restrict__ crossc,
                             float* __restrict__ out) {
  int wv = threadIdx.x >> 6, lane = threadIdx.x & 63;
  int b = blockIdx.x * 4 + wv;
  const float* wph = Wp + kInDim;
  float s = 0.f;
  #pragma unroll
  for (int k = lane; k < kH3; k += 64) {
    float h = a3[k] * b2f(z3[(size_t)b * kH3 + k]) + c3[k];
    s += h * wph[k];
  }
  #pragma unroll
  for (int off = 32; off; off >>= 1) s += __shfl_down(s, off, 64);
  if (lane == 0) {
    float logit = s + crossc[b] + bp[0];
    out[b] = 1.f / (1.f + expf(-logit));
  }
}

// ---------- workspace layout ----------
constexpr size_t OFF_X0    = 0;                                   // 16384*1728*2
constexpr size_t OFF_Z1    = OFF_X0 + (size_t)kBatch * kInPad * 2;
constexpr size_t OFF_Z2    = OFF_Z1 + (size_t)kBatch * kH1 * 2;
constexpr size_t OFF_Z3    = OFF_Z2 + (size_t)kBatch * kH2 * 2;
constexpr size_t OFF_W1T   = OFF_Z3 + (size_t)kBatch * kH3 * 2;
constexpr size_t OFF_W2T   = OFF_W1T + (size_t)kH1 * kInPad * 2;
constexpr size_t OFF_W3T   = OFF_W2T + (size_t)kH2 * kH1 * 2;
constexpr size_t OFF_CROSS = OFF_W3T + (size_t)kH3 * kH2 * 2;
constexpr size_t OFF_STATS = OFF_CROSS + (size_t)kBatch * 4;
constexpr size_t STATS_FLOATS = 2 * (kInPad + kH1 + kH2 + kH3);   // 7040
constexpr size_t OFF_AFF   = OFF_STATS + STATS_FLOATS * 4;
constexpr size_t OFF_MISC  = OFF_AFF + STATS_FLOATS * 4;
// total ~120.4 MB

extern "C" void kernel_launch(void* const* d_in, const int* in_sizes, int n_in,
                              void* d_out, int out_size, void* d_ws, size_t ws_size,
                              hipStream_t stream) {
  const int*   sparse  = (const int*)d_in[0];
  const float* dense   = (const float*)d_in[1];
  const float* emb     = (const float*)d_in[2];
  const float* w_cross = (const float*)d_in[3];
  const float* b_cross = (const float*)d_in[4];
  const float* bn0_g = (const float*)d_in[5],  *bn0_b = (const float*)d_in[6];
  const float* W1    = (const float*)d_in[7],  *bias1 = (const float*)d_in[8];
  const float* bn1_g = (const float*)d_in[9],  *bn1_b = (const float*)d_in[10];
  const float* W2    = (const float*)d_in[11], *bias2 = (const float*)d_in[12];
  const float* bn2_g = (const float*)d_in[13], *bn2_b = (const float*)d_in[14];
  const float* W3    = (const float*)d_in[15], *bias3 = (const float*)d_in[16];
  const float* bn3_g = (const float*)d_in[17], *bn3_b = (const float*)d_in[18];
  const float* Wp    = (const float*)d_in[19], *bp    = (const float*)d_in[20];

  char* ws = (char*)d_ws;
  u16* x0  = (u16*)(ws + OFF_X0);
  u16* z1  = (u16*)(ws + OFF_Z1);
  u16* z2  = (u16*)(ws + OFF_Z2);
  u16* z3  = (u16*)(ws + OFF_Z3);
  u16* W1t = (u16*)(ws + OFF_W1T);
  u16* W2t = (u16*)(ws + OFF_W2T);
  u16* W3t = (u16*)(ws + OFF_W3T);
  float* crossc = (float*)(ws + OFF_CROSS);
  float* stats  = (float*)(ws + OFF_STATS);
  float* sum0 = stats,            *sq0 = stats + kInPad;
  float* sum1 = sq0 + kInPad,     *sq1 = sum1 + kH1;
  float* sum2 = sq1 + kH1,        *sq2 = sum2 + kH2;
  float* sum3 = sq2 + kH2,        *sq3 = sum3 + kH3;
  float* aff = (float*)(ws + OFF_AFF);
  float* a0 = aff,            *c0 = aff + kInPad;
  float* a1 = c0 + kInPad,    *c1 = a1 + kH1;
  float* a2 = c1 + kH1,       *c2 = a2 + kH2;
  float* a3 = c2 + kH2,       *c3 = a3 + kH3;
  float* misc = (float*)(ws + OFF_MISC);
  float* out = (float*)d_out;

  const float invM = 1.f / (float)kBatch;

  hipMemsetAsync(stats, 0, STATS_FLOATS * 4, stream);
  prep_kernel<<<1, 256, 0, stream>>>(Wp, misc);
  transpose_kernel<<<dim3(kInPad / 64, kH1 / 64), 256, 0, stream>>>(W1, W1t, kInDim, kH1, kInPad);
  transpose_kernel<<<dim3(kH1 / 64, kH2 / 64), 256, 0, stream>>>(W2, W2t, kH1, kH2, kH1);
  transpose_kernel<<<dim3(kH2 / 64, kH3 / 64), 256, 0, stream>>>(W3, W3t, kH2, kH3, kH2);

  gather_kernel<<<kBatch, 256, 0, stream>>>(sparse, dense, emb, w_cross, b_cross, Wp, misc,
                                            x0, crossc);

  // layer 0: BN(x0) in place
  colstats_kernel<<<dim3(kInPad / 64, 32), 256, 0, stream>>>(x0, kInPad, kBatch / 32, sum0, sq0);
  bn_fin_kernel<<<(kInPad + 255) / 256, 256, 0, stream>>>(sum0, sq0, bn0_g, bn0_b, kInDim, kInPad, invM, a0, c0);
  norm_kernel<<<(int)(((size_t)kBatch * kInPad / 8 + 255) / 256), 256, 0, stream>>>(
      x0, a0, c0, kInPad, (long)kBatch * kInPad / 8);

  // layer 1
  gemm_kernel<<<dim3(kH1 / 128, kBatch / 128), 256, 0, stream>>>(x0, W1t, bias1, z1, kBatch, kH1, kInPad);
  colstats_kernel<<<dim3(kH1 / 64, 32), 256, 0, stream>>>(z1, kH1, kBatch / 32, sum1, sq1);
  bn_fin_kernel<<<(kH1 + 255) / 256, 256, 0, stream>>>(sum1, sq1, bn1_g, bn1_b, kH1, kH1, invM, a1, c1);
  norm_kernel<<<(int)(((size_t)kBatch * kH1 / 8 + 255) / 256), 256, 0, stream>>>(
      z1, a1, c1, kH1, (long)kBatch * kH1 / 8);

  // layer 2
  gemm_kernel<<<dim3(kH2 / 128, kBatch / 128), 256, 0, stream>>>(z1, W2t, bias2, z2, kBatch, kH2, kH1);
  colstats_kernel<<<dim3(kH2 / 64, 32), 256, 0, stream>>>(z2, kH2, kBatch / 32, sum2, sq2);
  bn_fin_kernel<<<(kH2 + 255) / 256, 256, 0, stream>>>(sum2, sq2, bn2_g, bn2_b, kH2, kH2, invM, a2, c2);
  norm_kernel<<<(int)(((size_t)kBatch * kH2 / 8 + 255) / 256), 256, 0, stream>>>(
      z2, a2, c2, kH2, (long)kBatch * kH2 / 8);

  // layer 3 (BN folded into final kernel)
  gemm_kernel<<<dim3(kH3 / 128, kBatch / 128), 256, 0, stream>>>(z2, W3t, bias3, z3, kBatch, kH3, kH2);
  colstats_kernel<<<dim3(kH3 / 64, 32), 256, 0, stream>>>(z3, kH3, kBatch / 32, sum3, sq3);
  bn_fin_kernel<<<1, 256, 0, stream>>>(sum3, sq3, bn3_g, bn3_b, kH3, kH3, invM, a3, c3);

  final_kernel<<<kBatch / 4, 256, 0, stream>>>(z3, a3, c3, Wp, bp, crossc, out);
}

// Round 3
// 360.537 us; speedup vs baseline: 1.0628x; 1.0628x over previous
//
#include <hip/hip_runtime.h>
#include <hip/hip_bf16.h>
#include <cstdint>
#include <cstddef>

#define AS1 __attribute__((address_space(1)))
#define AS3 __attribute__((address_space(3)))

typedef __attribute__((ext_vector_type(8))) short short8v;
typedef __attribute__((ext_vector_type(4))) float f32x4;
typedef unsigned short u16;

constexpr int kBatch = 16384;
constexpr int kNSp   = 26;
constexpr int kVocab = 50000;
constexpr int kEmb   = 64;
constexpr int kInDim = 1677;   // 26*64 + 13
constexpr int kInPad = 1728;   // padded to x64 for MFMA K
constexpr int kDense = 13;
constexpr int kH1 = 1024, kH2 = 512, kH3 = 256;
constexpr float kEps = 1e-5f;

// ---------- bf16 helpers (bits held in u16) ----------
__device__ __forceinline__ float b2f(u16 s) {
  unsigned u = ((unsigned)s) << 16;
  union { unsigned u; float f; } c; c.u = u; return c.f;
}
__device__ __forceinline__ u16 f2b(float f) {
  __hip_bfloat16 h = __float2bfloat16(f);   // RNE
  return __builtin_bit_cast(u16, h);
}

// ---------- prep: Swpc = sum_{j<1677} Wp[j] ----------
__global__ void prep_kernel(const float* __restrict__ Wp, float* __restrict__ misc) {
  __shared__ float red[256];
  float s = 0.f;
  for (int j = threadIdx.x; j < kInDim; j += 256) s += Wp[j];
  red[threadIdx.x] = s;
  __syncthreads();
  for (int k = 128; k > 0; k >>= 1) {
    if (threadIdx.x < k) red[threadIdx.x] += red[threadIdx.x + k];
    __syncthreads();
  }
  if (threadIdx.x == 0) misc[0] = red[0];
}

// ---------- init folded biases (before stats exist; reduces add onto these) ----------
__global__ void initbias_kernel(const float* __restrict__ b1, const float* __restrict__ b2,
                                const float* __restrict__ b3, float* __restrict__ f1,
                                float* __restrict__ f2, float* __restrict__ f3) {
  int i = blockIdx.x * 256 + threadIdx.x;
  if (i < kH1) f1[i] = b1[i];
  if (i < kH2) f2[i] = b2[i];
  if (i < kH3) f3[i] = b3[i];
}

// ---------- transpose to f32 (pad): W[K][N] -> Wtf[N][Kp] ----------
__global__ void transpose_f32_kernel(const float* __restrict__ W, float* __restrict__ Wtf,
                                     int K, int N, int Kp) {
  __shared__ float t[64][65];
  int kb = blockIdx.x * 64;
  int nb = blockIdx.y * 64;
  int c  = threadIdx.x & 63;
  int r0 = threadIdx.x >> 6;   // 0..3
  #pragma unroll
  for (int rr = 0; rr < 64; rr += 4) {
    int k = kb + rr + r0;
    t[rr + r0][c] = (k < K) ? W[(size_t)k * N + nb + c] : 0.f;
  }
  __syncthreads();
  #pragma unroll
  for (int rr = 0; rr < 64; rr += 4) {
    int n = nb + rr + r0;
    Wtf[(size_t)n * Kp + kb + c] = t[c][rr + r0];
  }
}

// ---------- transpose + BN-fold + bf16: Wt[n][k] = bf16(W[k][n] * a[k]) ----------
__global__ void transpose_fold_kernel(const float* __restrict__ W, const float* __restrict__ a,
                                      u16* __restrict__ Wt, int K, int N, int Kp) {
  __shared__ float t[64][65];
  int kb = blockIdx.x * 64;
  int nb = blockIdx.y * 64;
  int c  = threadIdx.x & 63;
  int r0 = threadIdx.x >> 6;
  #pragma unroll
  for (int rr = 0; rr < 64; rr += 4) {
    int k = kb + rr + r0;
    t[rr + r0][c] = (k < K) ? W[(size_t)k * N + nb + c] : 0.f;
  }
  __syncthreads();
  float ak = a[kb + c];
  #pragma unroll
  for (int rr = 0; rr < 64; rr += 4) {
    int n = nb + rr + r0;
    Wt[(size_t)n * Kp + kb + c] = f2b(t[c][rr + r0] * ak);
  }
}

// ---------- scale+cast pre-transposed f32 weights by a[k]: single rounding ----------
__global__ void scale_cast_kernel(const float* __restrict__ Wtf, const float* __restrict__ a,
                                  u16* __restrict__ Wt, int Kp, long n4) {
  long i = (long)blockIdx.x * 256 + threadIdx.x;
  if (i >= n4) return;
  long base = i * 4;
  int k = (int)(base % Kp);
  float4 w = *(const float4*)(Wtf + base);
  ushort4 o;
  o.x = f2b(w.x * a[k]);
  o.y = f2b(w.y * a[k + 1]);
  o.z = f2b(w.z * a[k + 2]);
  o.w = f2b(w.w * a[k + 3]);
  *(ushort4*)(Wt + base) = o;
}

// ---------- folded-bias reduce: bf[n] += sum_k c[k] * W[k][n] (k-chunked) ----------
__global__ void biasfold_kernel(const float* __restrict__ W, const float* __restrict__ cc,
                                float* __restrict__ bf, int K, int N) {
  int n = blockIdx.x * 256 + threadIdx.x;
  if (n >= N) return;
  int chunk = (K + 7) / 8;
  int k0 = blockIdx.y * chunk;
  int k1 = min(k0 + chunk, K);
  float s = 0.f;
  for (int k = k0; k < k1; ++k) s += cc[k] * W[(size_t)k * N + n];
  atomicAdd(&bf[n], s);
}

// ---------- gather: build raw x0 (bf16, padded) + per-row cross contribution ----------
__global__ void gather_kernel(const int* __restrict__ sparse, const float* __restrict__ dense,
                              const float* __restrict__ emb, const float* __restrict__ w_cross,
                              const float* __restrict__ b_cross, const float* __restrict__ Wp,
                              const float* __restrict__ misc, u16* __restrict__ x0,
                              float* __restrict__ crossc) {
  const int b = blockIdx.x;
  const int tid = threadIdx.x;
  const int idx = sparse[b * kNSp];       // only column 0 is used by the reference
  const float* wc2 = w_cross + 2 * kInDim;
  u16* xrow = x0 + (size_t)b * kInPad;
  float u = 0.f, v = 0.f;
  for (int q = tid; q < 416; q += 256) {  // 416 = 1664/4
    int p = q * 4;
    const float* src = emb + ((size_t)(p >> 6) * kVocab + idx) * kEmb + (p & 63);
    float4 val = *(const float4*)src;
    u += val.x * wc2[p] + val.y * wc2[p + 1] + val.z * wc2[p + 2] + val.w * wc2[p + 3];
    v += val.x * Wp[p]  + val.y * Wp[p + 1]  + val.z * Wp[p + 2]  + val.w * Wp[p + 3];
    ushort4 o;
    o.x = f2b(val.x); o.y = f2b(val.y); o.z = f2b(val.z); o.w = f2b(val.w);
    *(ushort4*)(xrow + p) = o;
  }
  int p = 1664 + tid;
  if (p < kInPad) {
    float val = 0.f;
    if (p < kInDim) {
      val = dense[b * kDense + (p - 1664)];
      u += val * wc2[p];
      v += val * Wp[p];
    }
    xrow[p] = f2b(val);
  }
  #pragma unroll
  for (int off = 32; off; off >>= 1) {
    u += __shfl_down(u, off, 64);
    v += __shfl_down(v, off, 64);
  }
  __shared__ float su[4], sv[4];
  int lane = tid & 63, wv = tid >> 6;
  if (lane == 0) { su[wv] = u; sv[wv] = v; }
  __syncthreads();
  if (tid == 0) {
    float uu = su[0] + su[1] + su[2] + su[3];
    float vv = sv[0] + sv[1] + sv[2] + sv[3];
    crossc[b] = (1.f + uu) * vv + b_cross[2] * misc[0];
  }
}

// ---------- per-column sums / sumsq over batch (x0 only) ----------
__global__ void colstats_kernel(const u16* __restrict__ X, int ld, int rpb,
                                float* __restrict__ sum, float* __restrict__ sq) {
  int c  = threadIdx.x & 63;
  int rg = threadIdx.x >> 6;   // 0..3
  int col = blockIdx.x * 64 + c;
  int r0  = blockIdx.y * rpb;
  float s = 0.f, s2 = 0.f;
  for (int r = r0 + rg; r < r0 + rpb; r += 4) {
    float v = b2f(X[(size_t)r * ld + col]);
    s += v; s2 += v * v;
  }
  __shared__ float sh[8][64];
  sh[rg][c] = s; sh[rg + 4][c] = s2;
  __syncthreads();
  if (rg == 0) atomicAdd(&sum[col], sh[0][c] + sh[1][c] + sh[2][c] + sh[3][c]);
  else if (rg == 1) atomicAdd(&sq[col], sh[4][c] + sh[5][c] + sh[6][c] + sh[7][c]);
}

// ---------- finalize BN affine: a = g*rsqrt(var+eps), c = b - a*mu ----------
__global__ void bn_fin_kernel(const float* __restrict__ sum, const float* __restrict__ sq,
                              const float* __restrict__ g, const float* __restrict__ bb,
                              int Nreal, int Npad, float invM,
                              float* __restrict__ a, float* __restrict__ c) {
  int j = blockIdx.x * 256 + threadIdx.x;
  if (j >= Npad) return;
  if (j < Nreal) {
    float mu  = sum[j] * invM;
    float var = sq[j] * invM - mu * mu;
    float aa  = g[j] * rsqrtf(var + kEps);
    a[j] = aa; c[j] = bb[j] - aa * mu;
  } else {
    a[j] = 0.f; c[j] = 0.f;   // padded: folded weight rows become exactly 0
  }
}

// ---------- bf16 MFMA GEMM: Z = A @ Bt^T + bias, fused column stats ----------
// 128x128 tile, BK=64, 4 waves (2x2), global_load_lds staging, XOR-swizzled LDS.
__global__ __launch_bounds__(256) void gemm_kernel(
    const u16* __restrict__ A, const u16* __restrict__ Bt,
    const float* __restrict__ bias, u16* __restrict__ Z,
    float* __restrict__ sum, float* __restrict__ sq,
    int M, int N, int Kp) {
  __shared__ char lds[32768];
  char* ldsA = lds;
  char* ldsB = lds + 16384;
  const int tid  = threadIdx.x;
  const int lane = tid & 63;
  const int wv   = tid >> 6;
  const int wr = wv >> 1, wc = wv & 1;
  const int r16 = lane & 15, kg = lane >> 4;
  const int m0 = blockIdx.y * 128;
  const int n0 = blockIdx.x * 128;
  const int ldb = Kp * 2;  // bytes per row

  const char* gA = (const char*)A + (size_t)m0 * ldb;
  const char* gB = (const char*)Bt + (size_t)n0 * ldb;

  // staging: 16KB tile = 4 rounds x 256 thr x 16B; LDS linear, global pre-swizzled
  const char* srcA[4]; const char* srcB[4]; int dst[4];
  #pragma unroll
  for (int rr = 0; rr < 4; ++rr) {
    int lb  = (rr * 256 + tid) * 16;
    int row = lb >> 7;          // /128B per row (64 bf16)
    int kb  = lb & 127;
    int kbs = kb ^ ((row & 7) << 4);
    dst[rr]  = lb;
    srcA[rr] = gA + (size_t)row * ldb + kbs;
    srcB[rr] = gB + (size_t)row * ldb + kbs;
  }

  f32x4 acc[4][4];
  #pragma unroll
  for (int m = 0; m < 4; ++m)
    #pragma unroll
    for (int n = 0; n < 4; ++n) acc[m][n] = (f32x4){0.f, 0.f, 0.f, 0.f};

  for (int k0 = 0; k0 < Kp; k0 += 64) {
    __syncthreads();
    #pragma unroll
    for (int rr = 0; rr < 4; ++rr)
      __builtin_amdgcn_global_load_lds((const AS1 unsigned*)(srcA[rr] + k0 * 2),
                                       (AS3 unsigned*)(ldsA + dst[rr]), 16, 0, 0);
    #pragma unroll
    for (int rr = 0; rr < 4; ++rr)
      __builtin_amdgcn_global_load_lds((const AS1 unsigned*)(srcB[rr] + k0 * 2),
                                       (AS3 unsigned*)(ldsB + dst[rr]), 16, 0, 0);
    asm volatile("s_waitcnt vmcnt(0)" ::: "memory");
    __syncthreads();
    #pragma unroll
    for (int kk = 0; kk < 2; ++kk) {
      short8v av[4], bv[4];
      #pragma unroll
      for (int m = 0; m < 4; ++m) {
        int row = wr * 64 + m * 16 + r16;
        int kb  = (kk * 64 + kg * 16) ^ ((row & 7) << 4);
        av[m] = *(const short8v*)(ldsA + row * 128 + kb);
      }
      #pragma unroll
      for (int n = 0; n < 4; ++n) {
        int row = wc * 64 + n * 16 + r16;
        int kb  = (kk * 64 + kg * 16) ^ ((row & 7) << 4);
        bv[n] = *(const short8v*)(ldsB + row * 128 + kb);
      }
      #pragma unroll
      for (int m = 0; m < 4; ++m)
        #pragma unroll
        for (int n = 0; n < 4; ++n)
          acc[m][n] = __builtin_amdgcn_mfma_f32_16x16x32_bf16(av[m], bv[n], acc[m][n], 0, 0, 0);
    }
  }
  // epilogue: C/D layout col=lane&15, row=(lane>>4)*4+j (verified m89/m91).
  // Fused per-column stats: kg-groups (lanes r16, r16+16, +32, +48) share a column.
  #pragma unroll
  for (int n = 0; n < 4; ++n) {
    int col = n0 + wc * 64 + n * 16 + r16;
    float bs = bias[col];
    float ps = 0.f, pq = 0.f;
    #pragma unroll
    for (int m = 0; m < 4; ++m) {
      int rbase = m0 + wr * 64 + m * 16 + kg * 4;
      #pragma unroll
      for (int j = 0; j < 4; ++j) {
        float val = acc[m][n][j] + bs;
        Z[(size_t)(rbase + j) * N + col] = f2b(val);
        ps += val; pq += val * val;
      }
    }
    ps += __shfl_xor(ps, 16, 64); ps += __shfl_xor(ps, 32, 64);
    pq += __shfl_xor(pq, 16, 64); pq += __shfl_xor(pq, 32, 64);
    if (lane < 16) {
      atomicAdd(&sum[col], ps);
      atomicAdd(&sq[col],  pq);
    }
  }
}

// ---------- final: fold BN3 + concat-dot + sigmoid (float32 out) ----------
__global__ void final_kernel(const u16* __restrict__ z3, const float* __restrict__ a3,
                             const float* __restrict__ c3, const float* __restrict__ Wp,
                             const float* __restrict__ bp, const float* __restrict__ crossc,
                             float* __restrict__ out) {
  int wv = threadIdx.x >> 6, lane = threadIdx.x & 63;
  int b = blockIdx.x * 4 + wv;
  const float* wph = Wp + kInDim;
  float s = 0.f;
  #pragma unroll
  for (int k = lane; k < kH3; k += 64) {
    float h = a3[k] * b2f(z3[(size_t)b * kH3 + k]) + c3[k];
    s += h * wph[k];
  }
  #pragma unroll
  for (int off = 32; off; off >>= 1) s += __shfl_down(s, off, 64);
  if (lane == 0) {
    float logit = s + crossc[b] + bp[0];
    out[b] = 1.f / (1.f + expf(-logit));
  }
}

// ---------- workspace layout ----------
constexpr size_t OFF_X0    = 0;                                   // 16384*1728*2
constexpr size_t OFF_Z1    = OFF_X0 + (size_t)kBatch * kInPad * 2;
constexpr size_t OFF_Z2    = OFF_Z1 + (size_t)kBatch * kH1 * 2;
constexpr size_t OFF_Z3    = OFF_Z2 + (size_t)kBatch * kH2 * 2;
constexpr size_t OFF_W1T   = OFF_Z3 + (size_t)kBatch * kH3 * 2;
constexpr size_t OFF_W2T   = OFF_W1T + (size_t)kH1 * kInPad * 2;
constexpr size_t OFF_W3T   = OFF_W2T + (size_t)kH2 * kH1 * 2;
constexpr size_t OFF_W2TF  = OFF_W3T + (size_t)kH3 * kH2 * 2;
constexpr size_t OFF_W3TF  = OFF_W2TF + (size_t)kH2 * kH1 * 4;
constexpr size_t OFF_CROSS = OFF_W3TF + (size_t)kH3 * kH2 * 4;
constexpr size_t OFF_STATS = OFF_CROSS + (size_t)kBatch * 4;
constexpr size_t STATS_FLOATS = 2 * (kInPad + kH1 + kH2 + kH3);   // 7040
constexpr size_t OFF_AFF   = OFF_STATS + STATS_FLOATS * 4;
constexpr size_t OFF_BF    = OFF_AFF + STATS_FLOATS * 4;          // 1792 floats
constexpr size_t OFF_MISC  = OFF_BF + (kH1 + kH2 + kH3) * 4;
// total ~123 MB

extern "C" void kernel_launch(void* const* d_in, const int* in_sizes, int n_in,
                              void* d_out, int out_size, void* d_ws, size_t ws_size,
                              hipStream_t stream) {
  const int*   sparse  = (const int*)d_in[0];
  const float* dense   = (const float*)d_in[1];
  const float* emb     = (const float*)d_in[2];
  const float* w_cross = (const float*)d_in[3];
  const float* b_cross = (const float*)d_in[4];
  const float* bn0_g = (const float*)d_in[5],  *bn0_b = (const float*)d_in[6];
  const float* W1    = (const float*)d_in[7],  *bias1 = (const float*)d_in[8];
  const float* bn1_g = (const float*)d_in[9],  *bn1_b = (const float*)d_in[10];
  const float* W2    = (const float*)d_in[11], *bias2 = (const float*)d_in[12];
  const float* bn2_g = (const float*)d_in[13], *bn2_b = (const float*)d_in[14];
  const float* W3    = (const float*)d_in[15], *bias3 = (const float*)d_in[16];
  const float* bn3_g = (const float*)d_in[17], *bn3_b = (const float*)d_in[18];
  const float* Wp    = (const float*)d_in[19], *bp    = (const float*)d_in[20];

  char* ws = (char*)d_ws;
  u16* x0  = (u16*)(ws + OFF_X0);
  u16* z1  = (u16*)(ws + OFF_Z1);
  u16* z2  = (u16*)(ws + OFF_Z2);
  u16* z3  = (u16*)(ws + OFF_Z3);
  u16* W1t = (u16*)(ws + OFF_W1T);
  u16* W2t = (u16*)(ws + OFF_W2T);
  u16* W3t = (u16*)(ws + OFF_W3T);
  float* W2tf = (float*)(ws + OFF_W2TF);
  float* W3tf = (float*)(ws + OFF_W3TF);
  float* crossc = (float*)(ws + OFF_CROSS);
  float* stats  = (float*)(ws + OFF_STATS);
  float* sum0 = stats,            *sq0 = stats + kInPad;
  float* sum1 = sq0 + kInPad,     *sq1 = sum1 + kH1;
  float* sum2 = sq1 + kH1,        *sq2 = sum2 + kH2;
  float* sum3 = sq2 + kH2,        *sq3 = sum3 + kH3;
  float* aff = (float*)(ws + OFF_AFF);
  float* a0 = aff,            *c0 = aff + kInPad;
  float* a1 = c0 + kInPad,    *c1 = a1 + kH1;
  float* a2 = c1 + kH1,       *c2 = a2 + kH2;
  float* a3 = c2 + kH2,       *c3 = a3 + kH3;
  float* bfold = (float*)(ws + OFF_BF);
  float* b1f = bfold, *b2f = b1f + kH1, *b3f = b2f + kH2;
  float* misc = (float*)(ws + OFF_MISC);
  float* out = (float*)d_out;

  const float invM = 1.f / (float)kBatch;

  hipMemsetAsync(stats, 0, STATS_FLOATS * 4, stream);
  initbias_kernel<<<kH1 / 256, 256, 0, stream>>>(bias1, bias2, bias3, b1f, b2f, b3f);
  prep_kernel<<<1, 256, 0, stream>>>(Wp, misc);
  transpose_f32_kernel<<<dim3(kH1 / 64, kH2 / 64), 256, 0, stream>>>(W2, W2tf, kH1, kH2, kH1);
  transpose_f32_kernel<<<dim3(kH2 / 64, kH3 / 64), 256, 0, stream>>>(W3, W3tf, kH2, kH3, kH2);

  gather_kernel<<<kBatch, 256, 0, stream>>>(sparse, dense, emb, w_cross, b_cross, Wp, misc,
                                            x0, crossc);

  // BN0 stats -> fold into W1/bias1
  colstats_kernel<<<dim3(kInPad / 64, 32), 256, 0, stream>>>(x0, kInPad, kBatch / 32, sum0, sq0);
  bn_fin_kernel<<<(kInPad + 255) / 256, 256, 0, stream>>>(sum0, sq0, bn0_g, bn0_b, kInDim, kInPad, invM, a0, c0);
  transpose_fold_kernel<<<dim3(kInPad / 64, kH1 / 64), 256, 0, stream>>>(W1, a0, W1t, kInDim, kH1, kInPad);
  biasfold_kernel<<<dim3(kH1 / 256, 8), 256, 0, stream>>>(W1, c0, b1f, kInDim, kH1);

  // layer 1 (stats fused into GEMM)
  gemm_kernel<<<dim3(kH1 / 128, kBatch / 128), 256, 0, stream>>>(x0, W1t, b1f, z1, sum1, sq1, kBatch, kH1, kInPad);
  bn_fin_kernel<<<(kH1 + 255) / 256, 256, 0, stream>>>(sum1, sq1, bn1_g, bn1_b, kH1, kH1, invM, a1, c1);
  scale_cast_kernel<<<(int)(((size_t)kH2 * kH1 / 4 + 255) / 256), 256, 0, stream>>>(
      W2tf, a1, W2t, kH1, (long)kH2 * kH1 / 4);
  biasfold_kernel<<<dim3(kH2 / 256, 8), 256, 0, stream>>>(W2, c1, b2f, kH1, kH2);

  // layer 2
  gemm_kernel<<<dim3(kH2 / 128, kBatch / 128), 256, 0, stream>>>(z1, W2t, b2f, z2, sum2, sq2, kBatch, kH2, kH1);
  bn_fin_kernel<<<(kH2 + 255) / 256, 256, 0, stream>>>(sum2, sq2, bn2_g, bn2_b, kH2, kH2, invM, a2, c2);
  scale_cast_kernel<<<(int)(((size_t)kH3 * kH2 / 4 + 255) / 256), 256, 0, stream>>>(
      W3tf, a2, W3t, kH2, (long)kH3 * kH2 / 4);
  biasfold_kernel<<<dim3(kH3 / 256, 8), 256, 0, stream>>>(W3, c2, b3f, kH2, kH3);

  // layer 3 (BN3 folded into final kernel)
  gemm_kernel<<<dim3(kH3 / 128, kBatch / 128), 256, 0, stream>>>(z2, W3t, b3f, z3, sum3, sq3, kBatch, kH3, kH2);
  bn_fin_kernel<<<1, 256, 0, stream>>>(sum3, sq3, bn3_g, bn3_b, kH3, kH3, invM, a3, c3);

  final_kernel<<<kBatch / 4, 256, 0, stream>>>(z3, a3, c3, Wp, bp, crossc, out);
}

// Round 4
// 255.988 us; speedup vs baseline: 1.4969x; 1.4084x over previous
//
#include <hip/hip_runtime.h>
#include <hip/hip_bf16.h>
#include <cstdint>
#include <cstddef>

#define AS1 __attribute__((address_space(1)))
#define AS3 __attribute__((address_space(3)))

typedef __attribute__((ext_vector_type(8))) short short8v;
typedef __attribute__((ext_vector_type(4))) float f32x4;
typedef unsigned short u16;

constexpr int kBatch = 16384;
constexpr int kNSp   = 26;
constexpr int kVocab = 50000;
constexpr int kEmb   = 64;
constexpr int kInDim = 1677;   // 26*64 + 13
constexpr int kInPad = 1728;   // padded to x64 for MFMA K
constexpr int kDense = 13;
constexpr int kH1 = 1024, kH2 = 512, kH3 = 256;
constexpr float kEps = 1e-5f;

// ---------- bf16 helpers (bits held in u16) ----------
__device__ __forceinline__ float b2f(u16 s) {
  unsigned u = ((unsigned)s) << 16;
  union { unsigned u; float f; } c; c.u = u; return c.f;
}
__device__ __forceinline__ u16 f2b(float f) {
  __hip_bfloat16 h = __float2bfloat16(f);   // RNE
  return __builtin_bit_cast(u16, h);
}

// ---------- prep: Swpc = sum_{j<1677} Wp[j] ----------
__global__ void prep_kernel(const float* __restrict__ Wp, float* __restrict__ misc) {
  __shared__ float red[256];
  float s = 0.f;
  for (int j = threadIdx.x; j < kInDim; j += 256) s += Wp[j];
  red[threadIdx.x] = s;
  __syncthreads();
  for (int k = 128; k > 0; k >>= 1) {
    if (threadIdx.x < k) red[threadIdx.x] += red[threadIdx.x + k];
    __syncthreads();
  }
  if (threadIdx.x == 0) misc[0] = red[0];
}

// ---------- gather: build raw x0 (bf16, padded) + per-row cross contribution ----------
__global__ void gather_kernel(const int* __restrict__ sparse, const float* __restrict__ dense,
                              const float* __restrict__ emb, const float* __restrict__ w_cross,
                              const float* __restrict__ b_cross, const float* __restrict__ Wp,
                              const float* __restrict__ misc, u16* __restrict__ x0,
                              float* __restrict__ crossc) {
  const int b = blockIdx.x;
  const int tid = threadIdx.x;
  const int idx = sparse[b * kNSp];       // only column 0 is used by the reference
  const float* wc2 = w_cross + 2 * kInDim;
  u16* xrow = x0 + (size_t)b * kInPad;
  float u = 0.f, v = 0.f;
  for (int q = tid; q < 416; q += 256) {  // 416 = 1664/4
    int p = q * 4;
    const float* src = emb + ((size_t)(p >> 6) * kVocab + idx) * kEmb + (p & 63);
    float4 val = *(const float4*)src;
    u += val.x * wc2[p] + val.y * wc2[p + 1] + val.z * wc2[p + 2] + val.w * wc2[p + 3];
    v += val.x * Wp[p]  + val.y * Wp[p + 1]  + val.z * Wp[p + 2]  + val.w * Wp[p + 3];
    ushort4 o;
    o.x = f2b(val.x); o.y = f2b(val.y); o.z = f2b(val.z); o.w = f2b(val.w);
    *(ushort4*)(xrow + p) = o;
  }
  int p = 1664 + tid;
  if (p < kInPad) {
    float val = 0.f;
    if (p < kInDim) {
      val = dense[b * kDense + (p - 1664)];
      u += val * wc2[p];
      v += val * Wp[p];
    }
    xrow[p] = f2b(val);
  }
  #pragma unroll
  for (int off = 32; off; off >>= 1) {
    u += __shfl_down(u, off, 64);
    v += __shfl_down(v, off, 64);
  }
  __shared__ float su[4], sv[4];
  int lane = tid & 63, wv = tid >> 6;
  if (lane == 0) { su[wv] = u; sv[wv] = v; }
  __syncthreads();
  if (tid == 0) {
    float uu = su[0] + su[1] + su[2] + su[3];
    float vv = sv[0] + sv[1] + sv[2] + sv[3];
    crossc[b] = (1.f + uu) * vv + b_cross[2] * misc[0];
  }
}

// ---------- per-column sums / sumsq over batch (x0 only) ----------
__global__ void colstats_kernel(const u16* __restrict__ X, int ld, int rpb,
                                float* __restrict__ sum, float* __restrict__ sq) {
  int c  = threadIdx.x & 63;
  int rg = threadIdx.x >> 6;   // 0..3
  int col = blockIdx.x * 64 + c;
  int r0  = blockIdx.y * rpb;
  float s = 0.f, s2 = 0.f;
  for (int r = r0 + rg; r < r0 + rpb; r += 4) {
    float v = b2f(X[(size_t)r * ld + col]);
    s += v; s2 += v * v;
  }
  __shared__ float sh[8][64];
  sh[rg][c] = s; sh[rg + 4][c] = s2;
  __syncthreads();
  if (rg == 0) atomicAdd(&sum[col], sh[0][c] + sh[1][c] + sh[2][c] + sh[3][c]);
  else if (rg == 1) atomicAdd(&sq[col], sh[4][c] + sh[5][c] + sh[6][c] + sh[7][c]);
}

// ---------- fused layer-boundary: BN-affine from stats + transpose + scale-fold
//            + wave-reduced bias-fold.  Wt[n][k] = bf16(W[k][n]*a[k]),
//            bfold[n] += sum_k c[k]*W[k][n].  One dispatch per layer boundary. ----------
__global__ void fold_kernel(const float* __restrict__ W, const float* __restrict__ sum,
                            const float* __restrict__ sq, const float* __restrict__ g,
                            const float* __restrict__ bb, float invM,
                            u16* __restrict__ Wt, float* __restrict__ bfold,
                            int K, int N, int Kp) {
  __shared__ float t[64][65];
  int kb = blockIdx.x * 64;
  int nb = blockIdx.y * 64;
  int c  = threadIdx.x & 63;
  int r0 = threadIdx.x >> 6;   // 0..3 (wave id: 64 consecutive tids = one wave)
  #pragma unroll
  for (int rr = 0; rr < 64; rr += 4) {
    int k = kb + rr + r0;
    t[rr + r0][c] = (k < K) ? W[(size_t)k * N + nb + c] : 0.f;
  }
  __syncthreads();
  // this thread's k for the store phase is fixed: k = kb + c
  int k = kb + c;
  float a = 0.f, cc = 0.f;
  if (k < K) {
    float mu  = sum[k] * invM;
    float var = sq[k] * invM - mu * mu;
    a  = g[k] * rsqrtf(var + kEps);
    cc = bb[k] - a * mu;
  }
  #pragma unroll
  for (int rr = 0; rr < 64; rr += 4) {
    int n = nb + rr + r0;           // uniform across the wave
    float w = t[c][rr + r0];
    Wt[(size_t)n * Kp + k] = f2b(w * a);
    float part = cc * w;            // contribution to bfold[n]
    #pragma unroll
    for (int off = 32; off; off >>= 1) part += __shfl_xor(part, off, 64);
    if (c == 0) atomicAdd(&bfold[n], part);
  }
}

// ---------- bf16 MFMA GEMM: Z = A @ Bt^T + (bias+bfold), fused column stats ----------
// 128x128 tile, BK=64, 4 waves (2x2), global_load_lds staging, XOR-swizzled LDS,
// XCD-aware block swizzle (each XCD: 16 contiguous m-blocks x all n-blocks).
__global__ __launch_bounds__(256) void gemm_kernel(
    const u16* __restrict__ A, const u16* __restrict__ Bt,
    const float* __restrict__ bias, const float* __restrict__ bfold,
    u16* __restrict__ Z, float* __restrict__ sum, float* __restrict__ sq,
    int M, int N, int Kp) {
  __shared__ char lds[32768];
  char* ldsA = lds;
  char* ldsB = lds + 16384;
  const int tid  = threadIdx.x;
  const int lane = tid & 63;
  const int wv   = tid >> 6;
  const int wr = wv >> 1, wc = wv & 1;
  const int r16 = lane & 15, kg = lane >> 4;

  // XCD swizzle: L%8 = xcd; each xcd gets m-blocks [xcd*16, xcd*16+16) x all n-blocks.
  const int L   = blockIdx.y * gridDim.x + blockIdx.x;
  const int xcd = L & 7;
  const int j   = L >> 3;
  const int mb  = xcd * 16 + (j & 15);
  const int nb  = j >> 4;
  const int m0 = mb * 128;
  const int n0 = nb * 128;
  const int ldb = Kp * 2;  // bytes per row

  const char* gA = (const char*)A + (size_t)m0 * ldb;
  const char* gB = (const char*)Bt + (size_t)n0 * ldb;

  // staging: 16KB tile = 4 rounds x 256 thr x 16B; LDS linear, global pre-swizzled
  const char* srcA[4]; const char* srcB[4]; int dst[4];
  #pragma unroll
  for (int rr = 0; rr < 4; ++rr) {
    int lb  = (rr * 256 + tid) * 16;
    int row = lb >> 7;          // /128B per row (64 bf16)
    int kb  = lb & 127;
    int kbs = kb ^ ((row & 7) << 4);
    dst[rr]  = lb;
    srcA[rr] = gA + (size_t)row * ldb + kbs;
    srcB[rr] = gB + (size_t)row * ldb + kbs;
  }

  f32x4 acc[4][4];
  #pragma unroll
  for (int m = 0; m < 4; ++m)
    #pragma unroll
    for (int n = 0; n < 4; ++n) acc[m][n] = (f32x4){0.f, 0.f, 0.f, 0.f};

  for (int k0 = 0; k0 < Kp; k0 += 64) {
    __syncthreads();
    #pragma unroll
    for (int rr = 0; rr < 4; ++rr)
      __builtin_amdgcn_global_load_lds((const AS1 unsigned*)(srcA[rr] + k0 * 2),
                                       (AS3 unsigned*)(ldsA + dst[rr]), 16, 0, 0);
    #pragma unroll
    for (int rr = 0; rr < 4; ++rr)
      __builtin_amdgcn_global_load_lds((const AS1 unsigned*)(srcB[rr] + k0 * 2),
                                       (AS3 unsigned*)(ldsB + dst[rr]), 16, 0, 0);
    asm volatile("s_waitcnt vmcnt(0)" ::: "memory");
    __syncthreads();
    #pragma unroll
    for (int kk = 0; kk < 2; ++kk) {
      short8v av[4], bv[4];
      #pragma unroll
      for (int m = 0; m < 4; ++m) {
        int row = wr * 64 + m * 16 + r16;
        int kb  = (kk * 64 + kg * 16) ^ ((row & 7) << 4);
        av[m] = *(const short8v*)(ldsA + row * 128 + kb);
      }
      #pragma unroll
      for (int n = 0; n < 4; ++n) {
        int row = wc * 64 + n * 16 + r16;
        int kb  = (kk * 64 + kg * 16) ^ ((row & 7) << 4);
        bv[n] = *(const short8v*)(ldsB + row * 128 + kb);
      }
      #pragma unroll
      for (int m = 0; m < 4; ++m)
        #pragma unroll
        for (int n = 0; n < 4; ++n)
          acc[m][n] = __builtin_amdgcn_mfma_f32_16x16x32_bf16(av[m], bv[n], acc[m][n], 0, 0, 0);
    }
  }
  // epilogue: C/D layout col=lane&15, row=(lane>>4)*4+j (verified m89/m91).
  // Fused per-column stats: kg-groups (lanes r16, r16+16, +32, +48) share a column.
  #pragma unroll
  for (int n = 0; n < 4; ++n) {
    int col = n0 + wc * 64 + n * 16 + r16;
    float bs = bias[col] + bfold[col];
    float ps = 0.f, pq = 0.f;
    #pragma unroll
    for (int m = 0; m < 4; ++m) {
      int rbase = m0 + wr * 64 + m * 16 + kg * 4;
      #pragma unroll
      for (int j2 = 0; j2 < 4; ++j2) {
        float val = acc[m][n][j2] + bs;
        Z[(size_t)(rbase + j2) * N + col] = f2b(val);
        ps += val; pq += val * val;
      }
    }
    ps += __shfl_xor(ps, 16, 64); ps += __shfl_xor(ps, 32, 64);
    pq += __shfl_xor(pq, 16, 64); pq += __shfl_xor(pq, 32, 64);
    if (lane < 16) {
      atomicAdd(&sum[col], ps);
      atomicAdd(&sq[col],  pq);
    }
  }
}

// ---------- final: BN3 inline from stats + concat-dot + sigmoid (float32 out) ----------
__global__ void final_kernel(const u16* __restrict__ z3, const float* __restrict__ sum3,
                             const float* __restrict__ sq3, const float* __restrict__ g3,
                             const float* __restrict__ b3, float invM,
                             const float* __restrict__ Wp, const float* __restrict__ bp,
                             const float* __restrict__ crossc, float* __restrict__ out) {
  int wv = threadIdx.x >> 6, lane = threadIdx.x & 63;
  int b = blockIdx.x * 4 + wv;
  const float* wph = Wp + kInDim;
  float s = 0.f;
  #pragma unroll
  for (int k = lane; k < kH3; k += 64) {
    float mu  = sum3[k] * invM;
    float var = sq3[k] * invM - mu * mu;
    float a   = g3[k] * rsqrtf(var + kEps);
    float cc  = b3[k] - a * mu;
    float h = a * b2f(z3[(size_t)b * kH3 + k]) + cc;
    s += h * wph[k];
  }
  #pragma unroll
  for (int off = 32; off; off >>= 1) s += __shfl_down(s, off, 64);
  if (lane == 0) {
    float logit = s + crossc[b] + bp[0];
    out[b] = 1.f / (1.f + expf(-logit));
  }
}

// ---------- workspace layout ----------
constexpr size_t OFF_X0    = 0;                                   // 16384*1728*2
constexpr size_t OFF_Z1    = OFF_X0 + (size_t)kBatch * kInPad * 2;
constexpr size_t OFF_Z2    = OFF_Z1 + (size_t)kBatch * kH1 * 2;
constexpr size_t OFF_Z3    = OFF_Z2 + (size_t)kBatch * kH2 * 2;
constexpr size_t OFF_W1T   = OFF_Z3 + (size_t)kBatch * kH3 * 2;
constexpr size_t OFF_W2T   = OFF_W1T + (size_t)kH1 * kInPad * 2;
constexpr size_t OFF_W3T   = OFF_W2T + (size_t)kH2 * kH1 * 2;
constexpr size_t OFF_CROSS = OFF_W3T + (size_t)kH3 * kH2 * 2;
constexpr size_t OFF_STATS = OFF_CROSS + (size_t)kBatch * 4;
constexpr size_t STATS_FLOATS = 2 * (kInPad + kH1 + kH2 + kH3);   // 7040
constexpr size_t BF_FLOATS = kH1 + kH2 + kH3;                      // 1792
constexpr size_t OFF_BF    = OFF_STATS + STATS_FLOATS * 4;         // zeroed with stats
constexpr size_t OFF_MISC  = OFF_BF + BF_FLOATS * 4;
// total ~113 MB

extern "C" void kernel_launch(void* const* d_in, const int* in_sizes, int n_in,
                              void* d_out, int out_size, void* d_ws, size_t ws_size,
                              hipStream_t stream) {
  const int*   sparse  = (const int*)d_in[0];
  const float* dense   = (const float*)d_in[1];
  const float* emb     = (const float*)d_in[2];
  const float* w_cross = (const float*)d_in[3];
  const float* b_cross = (const float*)d_in[4];
  const float* bn0_g = (const float*)d_in[5],  *bn0_b = (const float*)d_in[6];
  const float* W1    = (const float*)d_in[7],  *bias1 = (const float*)d_in[8];
  const float* bn1_g = (const float*)d_in[9],  *bn1_b = (const float*)d_in[10];
  const float* W2    = (const float*)d_in[11], *bias2 = (const float*)d_in[12];
  const float* bn2_g = (const float*)d_in[13], *bn2_b = (const float*)d_in[14];
  const float* W3    = (const float*)d_in[15], *bias3 = (const float*)d_in[16];
  const float* bn3_g = (const float*)d_in[17], *bn3_b = (const float*)d_in[18];
  const float* Wp    = (const float*)d_in[19], *bp    = (const float*)d_in[20];

  char* ws = (char*)d_ws;
  u16* x0  = (u16*)(ws + OFF_X0);
  u16* z1  = (u16*)(ws + OFF_Z1);
  u16* z2  = (u16*)(ws + OFF_Z2);
  u16* z3  = (u16*)(ws + OFF_Z3);
  u16* W1t = (u16*)(ws + OFF_W1T);
  u16* W2t = (u16*)(ws + OFF_W2T);
  u16* W3t = (u16*)(ws + OFF_W3T);
  float* crossc = (float*)(ws + OFF_CROSS);
  float* stats  = (float*)(ws + OFF_STATS);
  float* sum0 = stats,            *sq0 = stats + kInPad;
  float* sum1 = sq0 + kInPad,     *sq1 = sum1 + kH1;
  float* sum2 = sq1 + kH1,        *sq2 = sum2 + kH2;
  float* sum3 = sq2 + kH2,        *sq3 = sum3 + kH3;
  float* bfold = (float*)(ws + OFF_BF);
  float* b1f = bfold, *b2f = b1f + kH1, *b3f = b2f + kH2;
  float* misc = (float*)(ws + OFF_MISC);
  float* out = (float*)d_out;

  const float invM = 1.f / (float)kBatch;

  // zero stats + bias-fold accumulators (contiguous region)
  hipMemsetAsync(stats, 0, (STATS_FLOATS + BF_FLOATS) * 4, stream);
  prep_kernel<<<1, 256, 0, stream>>>(Wp, misc);

  gather_kernel<<<kBatch, 256, 0, stream>>>(sparse, dense, emb, w_cross, b_cross, Wp, misc,
                                            x0, crossc);

  // BN0 stats -> fold into W1/bias1 (one dispatch)
  colstats_kernel<<<dim3(kInPad / 64, 32), 256, 0, stream>>>(x0, kInPad, kBatch / 32, sum0, sq0);
  fold_kernel<<<dim3(kInPad / 64, kH1 / 64), 256, 0, stream>>>(
      W1, sum0, sq0, bn0_g, bn0_b, invM, W1t, b1f, kInDim, kH1, kInPad);

  // layer 1 (stats fused into GEMM)
  gemm_kernel<<<dim3(kH1 / 128, kBatch / 128), 256, 0, stream>>>(
      x0, W1t, bias1, b1f, z1, sum1, sq1, kBatch, kH1, kInPad);
  fold_kernel<<<dim3(kH1 / 64, kH2 / 64), 256, 0, stream>>>(
      W2, sum1, sq1, bn1_g, bn1_b, invM, W2t, b2f, kH1, kH2, kH1);

  // layer 2
  gemm_kernel<<<dim3(kH2 / 128, kBatch / 128), 256, 0, stream>>>(
      z1, W2t, bias2, b2f, z2, sum2, sq2, kBatch, kH2, kH1);
  fold_kernel<<<dim3(kH2 / 64, kH3 / 64), 256, 0, stream>>>(
      W3, sum2, sq2, bn2_g, bn2_b, invM, W3t, b3f, kH2, kH3, kH2);

  // layer 3 (BN3 inline in final)
  gemm_kernel<<<dim3(kH3 / 128, kBatch / 128), 256, 0, stream>>>(
      z2, W3t, bias3, b3f, z3, sum3, sq3, kBatch, kH3, kH2);

  final_kernel<<<kBatch / 4, 256, 0, stream>>>(z3, sum3, sq3, bn3_g, bn3_b, invM,
                                               Wp, bp, crossc, out);
}

// Round 5
// 242.326 us; speedup vs baseline: 1.5813x; 1.0564x over previous
//
#include <hip/hip_runtime.h>
#include <hip/hip_bf16.h>
#include <cstdint>
#include <cstddef>

#define AS1 __attribute__((address_space(1)))
#define AS3 __attribute__((address_space(3)))

typedef __attribute__((ext_vector_type(8))) short short8v;
typedef __attribute__((ext_vector_type(4))) float f32x4;
typedef unsigned short u16;

constexpr int kBatch = 16384;
constexpr int kNSp   = 26;
constexpr int kVocab = 50000;
constexpr int kEmb   = 64;
constexpr int kInDim = 1677;   // 26*64 + 13
constexpr int kInPad = 1792;   // padded to x128 for the 2-K-tile/iter pipeline
constexpr int kDense = 13;
constexpr int kH1 = 1024, kH2 = 512, kH3 = 256;
constexpr float kEps = 1e-5f;

// ---------- bf16 helpers (bits held in u16) ----------
__device__ __forceinline__ float b2f(u16 s) {
  unsigned u = ((unsigned)s) << 16;
  union { unsigned u; float f; } c; c.u = u; return c.f;
}
__device__ __forceinline__ u16 f2b(float f) {
  __hip_bfloat16 h = __float2bfloat16(f);   // RNE
  return __builtin_bit_cast(u16, h);
}

// ---------- prep: Swpc = sum_{j<1677} Wp[j] ----------
__global__ void prep_kernel(const float* __restrict__ Wp, float* __restrict__ misc) {
  __shared__ float red[256];
  float s = 0.f;
  for (int j = threadIdx.x; j < kInDim; j += 256) s += Wp[j];
  red[threadIdx.x] = s;
  __syncthreads();
  for (int k = 128; k > 0; k >>= 1) {
    if (threadIdx.x < k) red[threadIdx.x] += red[threadIdx.x + k];
    __syncthreads();
  }
  if (threadIdx.x == 0) misc[0] = red[0];
}

// ---------- gather: build raw x0 (bf16, padded) + per-row cross contribution ----------
__global__ void gather_kernel(const int* __restrict__ sparse, const float* __restrict__ dense,
                              const float* __restrict__ emb, const float* __restrict__ w_cross,
                              const float* __restrict__ b_cross, const float* __restrict__ Wp,
                              const float* __restrict__ misc, u16* __restrict__ x0,
                              float* __restrict__ crossc) {
  const int b = blockIdx.x;
  const int tid = threadIdx.x;
  const int idx = sparse[b * kNSp];       // only column 0 is used by the reference
  const float* wc2 = w_cross + 2 * kInDim;
  u16* xrow = x0 + (size_t)b * kInPad;
  float u = 0.f, v = 0.f;
  for (int q = tid; q < 416; q += 256) {  // 416 = 1664/4
    int p = q * 4;
    const float* src = emb + ((size_t)(p >> 6) * kVocab + idx) * kEmb + (p & 63);
    float4 val = *(const float4*)src;
    u += val.x * wc2[p] + val.y * wc2[p + 1] + val.z * wc2[p + 2] + val.w * wc2[p + 3];
    v += val.x * Wp[p]  + val.y * Wp[p + 1]  + val.z * Wp[p + 2]  + val.w * Wp[p + 3];
    ushort4 o;
    o.x = f2b(val.x); o.y = f2b(val.y); o.z = f2b(val.z); o.w = f2b(val.w);
    *(ushort4*)(xrow + p) = o;
  }
  int p = 1664 + tid;
  if (p < kInPad) {
    float val = 0.f;
    if (p < kInDim) {
      val = dense[b * kDense + (p - 1664)];
      u += val * wc2[p];
      v += val * Wp[p];
    }
    xrow[p] = f2b(val);
  }
  #pragma unroll
  for (int off = 32; off; off >>= 1) {
    u += __shfl_down(u, off, 64);
    v += __shfl_down(v, off, 64);
  }
  __shared__ float su[4], sv[4];
  int lane = tid & 63, wv = tid >> 6;
  if (lane == 0) { su[wv] = u; sv[wv] = v; }
  __syncthreads();
  if (tid == 0) {
    float uu = su[0] + su[1] + su[2] + su[3];
    float vv = sv[0] + sv[1] + sv[2] + sv[3];
    crossc[b] = (1.f + uu) * vv + b_cross[2] * misc[0];
  }
}

// ---------- per-column sums / sumsq over batch (x0 only) ----------
__global__ void colstats_kernel(const u16* __restrict__ X, int ld, int rpb,
                                float* __restrict__ sum, float* __restrict__ sq) {
  int c  = threadIdx.x & 63;
  int rg = threadIdx.x >> 6;   // 0..3
  int col = blockIdx.x * 64 + c;
  int r0  = blockIdx.y * rpb;
  float s = 0.f, s2 = 0.f;
  for (int r = r0 + rg; r < r0 + rpb; r += 4) {
    float v = b2f(X[(size_t)r * ld + col]);
    s += v; s2 += v * v;
  }
  __shared__ float sh[8][64];
  sh[rg][c] = s; sh[rg + 4][c] = s2;
  __syncthreads();
  if (rg == 0) atomicAdd(&sum[col], sh[0][c] + sh[1][c] + sh[2][c] + sh[3][c]);
  else if (rg == 1) atomicAdd(&sq[col], sh[4][c] + sh[5][c] + sh[6][c] + sh[7][c]);
}

// ---------- fused layer-boundary: BN-affine from stats + transpose + scale-fold
//            + wave-reduced bias-fold. ----------
__global__ void fold_kernel(const float* __restrict__ W, const float* __restrict__ sum,
                            const float* __restrict__ sq, const float* __restrict__ g,
                            const float* __restrict__ bb, float invM,
                            u16* __restrict__ Wt, float* __restrict__ bfold,
                            int K, int N, int Kp) {
  __shared__ float t[64][65];
  int kb = blockIdx.x * 64;
  int nb = blockIdx.y * 64;
  int c  = threadIdx.x & 63;
  int r0 = threadIdx.x >> 6;   // 0..3
  #pragma unroll
  for (int rr = 0; rr < 64; rr += 4) {
    int k = kb + rr + r0;
    t[rr + r0][c] = (k < K) ? W[(size_t)k * N + nb + c] : 0.f;
  }
  __syncthreads();
  int k = kb + c;
  float a = 0.f, cc = 0.f;
  if (k < K) {
    float mu  = sum[k] * invM;
    float var = sq[k] * invM - mu * mu;
    a  = g[k] * rsqrtf(var + kEps);
    cc = bb[k] - a * mu;
  }
  #pragma unroll
  for (int rr = 0; rr < 64; rr += 4) {
    int n = nb + rr + r0;
    float w = t[c][rr + r0];
    Wt[(size_t)n * Kp + k] = f2b(w * a);
    float part = cc * w;
    #pragma unroll
    for (int off = 32; off; off >>= 1) part += __shfl_xor(part, off, 64);
    if (c == 0) atomicAdd(&bfold[n], part);
  }
}

// ---------- 128x128 MFMA GEMM (verified m97-structure) for layers 2,3 ----------
__global__ __launch_bounds__(256) void gemm_kernel(
    const u16* __restrict__ A, const u16* __restrict__ Bt,
    const float* __restrict__ bias, const float* __restrict__ bfold,
    u16* __restrict__ Z, float* __restrict__ sum, float* __restrict__ sq,
    int M, int N, int Kp) {
  __shared__ char lds[32768];
  char* ldsA = lds;
  char* ldsB = lds + 16384;
  const int tid  = threadIdx.x;
  const int lane = tid & 63;
  const int wv   = tid >> 6;
  const int wr = wv >> 1, wc = wv & 1;
  const int r16 = lane & 15, kg = lane >> 4;

  const int L   = blockIdx.y * gridDim.x + blockIdx.x;
  const int xcd = L & 7;
  const int j   = L >> 3;
  const int mb  = xcd * 16 + (j & 15);
  const int nb  = j >> 4;
  const int m0 = mb * 128;
  const int n0 = nb * 128;
  const int ldb = Kp * 2;

  const char* gA = (const char*)A + (size_t)m0 * ldb;
  const char* gB = (const char*)Bt + (size_t)n0 * ldb;

  const char* srcA[4]; const char* srcB[4]; int dst[4];
  #pragma unroll
  for (int rr = 0; rr < 4; ++rr) {
    int lb  = (rr * 256 + tid) * 16;
    int row = lb >> 7;
    int kb  = lb & 127;
    int kbs = kb ^ ((row & 7) << 4);
    dst[rr]  = lb;
    srcA[rr] = gA + (size_t)row * ldb + kbs;
    srcB[rr] = gB + (size_t)row * ldb + kbs;
  }

  f32x4 acc[4][4];
  #pragma unroll
  for (int m = 0; m < 4; ++m)
    #pragma unroll
    for (int n = 0; n < 4; ++n) acc[m][n] = (f32x4){0.f, 0.f, 0.f, 0.f};

  for (int k0 = 0; k0 < Kp; k0 += 64) {
    __syncthreads();
    #pragma unroll
    for (int rr = 0; rr < 4; ++rr)
      __builtin_amdgcn_global_load_lds((const AS1 unsigned*)(srcA[rr] + k0 * 2),
                                       (AS3 unsigned*)(ldsA + dst[rr]), 16, 0, 0);
    #pragma unroll
    for (int rr = 0; rr < 4; ++rr)
      __builtin_amdgcn_global_load_lds((const AS1 unsigned*)(srcB[rr] + k0 * 2),
                                       (AS3 unsigned*)(ldsB + dst[rr]), 16, 0, 0);
    asm volatile("s_waitcnt vmcnt(0)" ::: "memory");
    __syncthreads();
    #pragma unroll
    for (int kk = 0; kk < 2; ++kk) {
      short8v av[4], bv[4];
      #pragma unroll
      for (int m = 0; m < 4; ++m) {
        int row = wr * 64 + m * 16 + r16;
        int kb  = (kk * 64 + kg * 16) ^ ((row & 7) << 4);
        av[m] = *(const short8v*)(ldsA + row * 128 + kb);
      }
      #pragma unroll
      for (int n = 0; n < 4; ++n) {
        int row = wc * 64 + n * 16 + r16;
        int kb  = (kk * 64 + kg * 16) ^ ((row & 7) << 4);
        bv[n] = *(const short8v*)(ldsB + row * 128 + kb);
      }
      #pragma unroll
      for (int m = 0; m < 4; ++m)
        #pragma unroll
        for (int n = 0; n < 4; ++n)
          acc[m][n] = __builtin_amdgcn_mfma_f32_16x16x32_bf16(av[m], bv[n], acc[m][n], 0, 0, 0);
    }
  }
  #pragma unroll
  for (int n = 0; n < 4; ++n) {
    int col = n0 + wc * 64 + n * 16 + r16;
    float bs = bias[col] + bfold[col];
    float ps = 0.f, pq = 0.f;
    #pragma unroll
    for (int m = 0; m < 4; ++m) {
      int rbase = m0 + wr * 64 + m * 16 + kg * 4;
      #pragma unroll
      for (int j2 = 0; j2 < 4; ++j2) {
        float val = acc[m][n][j2] + bs;
        Z[(size_t)(rbase + j2) * N + col] = f2b(val);
        ps += val; pq += val * val;
      }
    }
    ps += __shfl_xor(ps, 16, 64); ps += __shfl_xor(ps, 32, 64);
    pq += __shfl_xor(pq, 16, 64); pq += __shfl_xor(pq, 32, 64);
    if (lane < 16) {
      atomicAdd(&sum[col], ps);
      atomicAdd(&sq[col],  pq);
    }
  }
}

// ---------- 256x256 8-wave 4-phase/K-tile pipelined GEMM (layer 1) ----------
// BK=64, LDS 128KB double-buffered, half-tile staging, counted vmcnt(8),
// raw s_barrier (no implicit vmcnt(0) drain), setprio around MFMA clusters.
// Quadrant order per K-tile: (A0,B0),(A0,B1),(A1,B0),(A1,B1).
// Stage slots per K-tile T: p1:B1(T+1) p2:A1(T+1) p3:A0(T+2) p4:B0(T+2).
// Ledger verified: every overwrite >=1 barrier after last read; vmcnt(8)
// leaves exactly the 4 not-yet-needed halves (8 loads) in flight.

#define STAGE(OP, H, TILE)                                                      \
  {                                                                             \
    const char* sb = ((OP) ? gB : gA) + (size_t)((H) * 128) * ldb               \
                     + (size_t)(TILE) * 128 + srcoff;                           \
    char* db = lds + (((TILE) & 1) << 16) + ((OP) << 15) + ((H) << 14) + tid * 16; \
    __builtin_amdgcn_global_load_lds((const AS1 unsigned*)sb,                   \
                                     (AS3 unsigned*)db, 16, 0, 0);              \
    __builtin_amdgcn_global_load_lds((const AS1 unsigned*)(sb + 64 * (size_t)ldb), \
                                     (AS3 unsigned*)(db + 8192), 16, 0, 0);     \
  }

#define PHASE(T, MH, NH)                                                        \
  {                                                                             \
    char* la  = lds + (((T) & 1) << 16);                                        \
    char* lbp = la + 32768;                                                     \
    short8v av[4][2], bv[2][2];                                                 \
    _Pragma("unroll")                                                           \
    for (int fm = 0; fm < 4; ++fm) {                                            \
      int row = (MH) * 128 + wr * 64 + fm * 16 + r16;                           \
      _Pragma("unroll")                                                         \
      for (int kk = 0; kk < 2; ++kk) {                                          \
        int kb = (kk * 64 + kg * 16) ^ ((row & 7) << 4);                        \
        av[fm][kk] = *(const short8v*)(la + row * 128 + kb);                    \
      }                                                                         \
    }                                                                           \
    _Pragma("unroll")                                                           \
    for (int fn = 0; fn < 2; ++fn) {                                            \
      int row = (NH) * 128 + wc * 32 + fn * 16 + r16;                           \
      _Pragma("unroll")                                                         \
      for (int kk = 0; kk < 2; ++kk) {                                          \
        int kb = (kk * 64 + kg * 16) ^ ((row & 7) << 4);                        \
        bv[fn][kk] = *(const short8v*)(lbp + row * 128 + kb);                   \
      }                                                                         \
    }                                                                           \
    __builtin_amdgcn_s_setprio(1);                                              \
    _Pragma("unroll")                                                           \
    for (int fm = 0; fm < 4; ++fm)                                              \
      _Pragma("unroll")                                                         \
      for (int fn = 0; fn < 2; ++fn)                                            \
        _Pragma("unroll")                                                       \
        for (int kk = 0; kk < 2; ++kk)                                          \
          acc[(MH) * 4 + fm][(NH) * 2 + fn] =                                   \
              __builtin_amdgcn_mfma_f32_16x16x32_bf16(                          \
                  av[fm][kk], bv[fn][kk],                                       \
                  acc[(MH) * 4 + fm][(NH) * 2 + fn], 0, 0, 0);                  \
    __builtin_amdgcn_s_setprio(0);                                              \
  }

#define BAR_VM8()                                                               \
  {                                                                             \
    asm volatile("s_waitcnt vmcnt(8)" ::: "memory");                            \
    __builtin_amdgcn_sched_barrier(0);                                          \
    __builtin_amdgcn_s_barrier();                                               \
    __builtin_amdgcn_sched_barrier(0);                                          \
  }
#define BAR_NOVM()                                                              \
  {                                                                             \
    __builtin_amdgcn_sched_barrier(0);                                          \
    __builtin_amdgcn_s_barrier();                                               \
    __builtin_amdgcn_sched_barrier(0);                                          \
  }

__global__ __launch_bounds__(512, 2) void gemm256_kernel(
    const u16* __restrict__ A, const u16* __restrict__ Bt,
    const float* __restrict__ bias, const float* __restrict__ bfold,
    u16* __restrict__ Z, float* __restrict__ sum, float* __restrict__ sq,
    int M, int N, int Kp) {
  __shared__ char lds[131072];
  const int tid  = threadIdx.x;
  const int lane = tid & 63;
  const int wid  = tid >> 6;           // 0..7
  const int wr = wid >> 2, wc = wid & 3;  // 2M x 4N waves
  const int r16 = lane & 15, kg = lane >> 4;

  // XCD swizzle (grid divisible by 8)
  const int nmb = M >> 8;
  const int cpx = nmb >> 3;            // m-blocks per xcd
  const int L   = blockIdx.x;
  const int xcd = L & 7;
  const int jj  = L >> 3;
  const int mb  = xcd * cpx + (jj % cpx);
  const int nb  = jj / cpx;
  const int m0  = mb * 256;
  const int n0  = nb * 256;
  const int ldb = Kp * 2;
  const int nt  = Kp >> 6;             // K-tiles

  const char* gA = (const char*)A + (size_t)m0 * ldb;
  const char* gB = (const char*)Bt + (size_t)n0 * ldb;
  // per-thread staging offset: row0 = tid>>3 (0..63), 16B col (tid&7)*16, swizzled
  const int row0 = tid >> 3;
  const int kbs  = ((tid & 7) * 16) ^ ((row0 & 7) << 4);
  const size_t srcoff = (size_t)row0 * ldb + kbs;

  f32x4 acc[8][4];
  #pragma unroll
  for (int m = 0; m < 8; ++m)
    #pragma unroll
    for (int n = 0; n < 4; ++n) acc[m][n] = (f32x4){0.f, 0.f, 0.f, 0.f};

  // prologue: A0(0),B0(0),B1(0),A1(0),A0(1),B0(1) then vmcnt(8) -> tile0 A0,B0 landed
  STAGE(0, 0, 0); STAGE(1, 0, 0); STAGE(1, 1, 0); STAGE(0, 1, 0);
  STAGE(0, 0, 1); STAGE(1, 0, 1);
  BAR_VM8();

  for (int T = 0; T < nt; ++T) {
    // p1: quadrant (A0,B0); stage B1(T+1)
    if (T + 1 < nt) STAGE(1, 1, T + 1);
    PHASE(T, 0, 0);
    BAR_VM8();
    // p2: (A0,B1); stage A1(T+1)
    if (T + 1 < nt) STAGE(0, 1, T + 1);
    PHASE(T, 0, 1);
    BAR_VM8();
    // p3: (A1,B0); stage A0(T+2)
    if (T + 2 < nt) STAGE(0, 0, T + 2);
    PHASE(T, 1, 0);
    BAR_NOVM();
    // p4: (A1,B1); stage B0(T+2)
    if (T + 2 < nt) STAGE(1, 0, T + 2);
    PHASE(T, 1, 1);
    BAR_VM8();
  }

  // epilogue: C/D layout col=lane&15, row=kg*4+j; fused column stats
  #pragma unroll
  for (int nh = 0; nh < 2; ++nh)
    #pragma unroll
    for (int fn = 0; fn < 2; ++fn) {
      int col = n0 + nh * 128 + wc * 32 + fn * 16 + r16;
      float bs = bias[col] + bfold[col];
      float ps = 0.f, pq = 0.f;
      #pragma unroll
      for (int mh = 0; mh < 2; ++mh)
        #pragma unroll
        for (int fm = 0; fm < 4; ++fm) {
          int rbase = m0 + mh * 128 + wr * 64 + fm * 16 + kg * 4;
          #pragma unroll
          for (int j2 = 0; j2 < 4; ++j2) {
            float val = acc[mh * 4 + fm][nh * 2 + fn][j2] + bs;
            Z[(size_t)(rbase + j2) * N + col] = f2b(val);
            ps += val; pq += val * val;
          }
        }
      ps += __shfl_xor(ps, 16, 64); ps += __shfl_xor(ps, 32, 64);
      pq += __shfl_xor(pq, 16, 64); pq += __shfl_xor(pq, 32, 64);
      if (lane < 16) {
        atomicAdd(&sum[col], ps);
        atomicAdd(&sq[col],  pq);
      }
    }
}

// ---------- final: BN3 inline from stats + concat-dot + sigmoid (float32 out) ----------
__global__ void final_kernel(const u16* __restrict__ z3, const float* __restrict__ sum3,
                             const float* __restrict__ sq3, const float* __restrict__ g3,
                             const float* __restrict__ b3, float invM,
                             const float* __restrict__ Wp, const float* __restrict__ bp,
                             const float* __restrict__ crossc, float* __restrict__ out) {
  int wv = threadIdx.x >> 6, lane = threadIdx.x & 63;
  int b = blockIdx.x * 4 + wv;
  const float* wph = Wp + kInDim;
  float s = 0.f;
  #pragma unroll
  for (int k = lane; k < kH3; k += 64) {
    float mu  = sum3[k] * invM;
    float var = sq3[k] * invM - mu * mu;
    float a   = g3[k] * rsqrtf(var + kEps);
    float cc  = b3[k] - a * mu;
    float h = a * b2f(z3[(size_t)b * kH3 + k]) + cc;
    s += h * wph[k];
  }
  #pragma unroll
  for (int off = 32; off; off >>= 1) s += __shfl_down(s, off, 64);
  if (lane == 0) {
    float logit = s + crossc[b] + bp[0];
    out[b] = 1.f / (1.f + expf(-logit));
  }
}

// ---------- workspace layout ----------
constexpr size_t OFF_X0    = 0;                                   // 16384*1792*2
constexpr size_t OFF_Z1    = OFF_X0 + (size_t)kBatch * kInPad * 2;
constexpr size_t OFF_Z2    = OFF_Z1 + (size_t)kBatch * kH1 * 2;
constexpr size_t OFF_Z3    = OFF_Z2 + (size_t)kBatch * kH2 * 2;
constexpr size_t OFF_W1T   = OFF_Z3 + (size_t)kBatch * kH3 * 2;
constexpr size_t OFF_W2T   = OFF_W1T + (size_t)kH1 * kInPad * 2;
constexpr size_t OFF_W3T   = OFF_W2T + (size_t)kH2 * kH1 * 2;
constexpr size_t OFF_CROSS = OFF_W3T + (size_t)kH3 * kH2 * 2;
constexpr size_t OFF_STATS = OFF_CROSS + (size_t)kBatch * 4;
constexpr size_t STATS_FLOATS = 2 * (kInPad + kH1 + kH2 + kH3);   // 7168
constexpr size_t BF_FLOATS = kH1 + kH2 + kH3;                     // 1792
constexpr size_t OFF_BF    = OFF_STATS + STATS_FLOATS * 4;        // zeroed with stats
constexpr size_t OFF_MISC  = OFF_BF + BF_FLOATS * 4;
// total ~117 MB

extern "C" void kernel_launch(void* const* d_in, const int* in_sizes, int n_in,
                              void* d_out, int out_size, void* d_ws, size_t ws_size,
                              hipStream_t stream) {
  const int*   sparse  = (const int*)d_in[0];
  const float* dense   = (const float*)d_in[1];
  const float* emb     = (const float*)d_in[2];
  const float* w_cross = (const float*)d_in[3];
  const float* b_cross = (const float*)d_in[4];
  const float* bn0_g = (const float*)d_in[5],  *bn0_b = (const float*)d_in[6];
  const float* W1    = (const float*)d_in[7],  *bias1 = (const float*)d_in[8];
  const float* bn1_g = (const float*)d_in[9],  *bn1_b = (const float*)d_in[10];
  const float* W2    = (const float*)d_in[11], *bias2 = (const float*)d_in[12];
  const float* bn2_g = (const float*)d_in[13], *bn2_b = (const float*)d_in[14];
  const float* W3    = (const float*)d_in[15], *bias3 = (const float*)d_in[16];
  const float* bn3_g = (const float*)d_in[17], *bn3_b = (const float*)d_in[18];
  const float* Wp    = (const float*)d_in[19], *bp    = (const float*)d_in[20];

  char* ws = (char*)d_ws;
  u16* x0  = (u16*)(ws + OFF_X0);
  u16* z1  = (u16*)(ws + OFF_Z1);
  u16* z2  = (u16*)(ws + OFF_Z2);
  u16* z3  = (u16*)(ws + OFF_Z3);
  u16* W1t = (u16*)(ws + OFF_W1T);
  u16* W2t = (u16*)(ws + OFF_W2T);
  u16* W3t = (u16*)(ws + OFF_W3T);
  float* crossc = (float*)(ws + OFF_CROSS);
  float* stats  = (float*)(ws + OFF_STATS);
  float* sum0 = stats,            *sq0 = stats + kInPad;
  float* sum1 = sq0 + kInPad,     *sq1 = sum1 + kH1;
  float* sum2 = sq1 + kH1,        *sq2 = sum2 + kH2;
  float* sum3 = sq2 + kH2,        *sq3 = sum3 + kH3;
  float* bfold = (float*)(ws + OFF_BF);
  float* b1f = bfold, *b2f = b1f + kH1, *b3f = b2f + kH2;
  float* misc = (float*)(ws + OFF_MISC);
  float* out = (float*)d_out;

  const float invM = 1.f / (float)kBatch;

  hipMemsetAsync(stats, 0, (STATS_FLOATS + BF_FLOATS) * 4, stream);
  prep_kernel<<<1, 256, 0, stream>>>(Wp, misc);

  gather_kernel<<<kBatch, 256, 0, stream>>>(sparse, dense, emb, w_cross, b_cross, Wp, misc,
                                            x0, crossc);

  // BN0 stats -> fold into W1/bias1
  colstats_kernel<<<dim3(kInPad / 64, 32), 256, 0, stream>>>(x0, kInPad, kBatch / 32, sum0, sq0);
  fold_kernel<<<dim3(kInPad / 64, kH1 / 64), 256, 0, stream>>>(
      W1, sum0, sq0, bn0_g, bn0_b, invM, W1t, b1f, kInDim, kH1, kInPad);

  // layer 1: 256x256 8-phase pipelined GEMM (stats fused)
  gemm256_kernel<<<(kBatch / 256) * (kH1 / 256), 512, 0, stream>>>(
      x0, W1t, bias1, b1f, z1, sum1, sq1, kBatch, kH1, kInPad);
  fold_kernel<<<dim3(kH1 / 64, kH2 / 64), 256, 0, stream>>>(
      W2, sum1, sq1, bn1_g, bn1_b, invM, W2t, b2f, kH1, kH2, kH1);

  // layer 2
  gemm_kernel<<<dim3(kH2 / 128, kBatch / 128), 256, 0, stream>>>(
      z1, W2t, bias2, b2f, z2, sum2, sq2, kBatch, kH2, kH1);
  fold_kernel<<<dim3(kH2 / 64, kH3 / 64), 256, 0, stream>>>(
      W3, sum2, sq2, bn2_g, bn2_b, invM, W3t, b3f, kH2, kH3, kH2);

  // layer 3 (BN3 inline in final)
  gemm_kernel<<<dim3(kH3 / 128, kBatch / 128), 256, 0, stream>>>(
      z2, W3t, bias3, b3f, z3, sum3, sq3, kBatch, kH3, kH2);

  final_kernel<<<kBatch / 4, 256, 0, stream>>>(z3, sum3, sq3, bn3_g, bn3_b, invM,
                                               Wp, bp, crossc, out);
}